// Round 13
// baseline (152.759 us; speedup 1.0000x reference)
//
#include <hip/hip_runtime.h>
#include <math.h>

#define N_TOK 4096
#define CDIM  1024
#define NH    16
#define HD    64

// scores: |q̂γ · k̂γ√D| <= 8 (γ=1), folded to log2 domain via K scale.
#define KSCALE 11.5416469f   // 8 * log2(e)

typedef __attribute__((ext_vector_type(8)))  __bf16 bf16x8;
typedef __attribute__((ext_vector_type(2)))  float  f32x2;
typedef __attribute__((ext_vector_type(4)))  float  f32x4;
typedef __attribute__((ext_vector_type(16))) float  f32x16;
typedef __attribute__((ext_vector_type(4)))  unsigned int u32x4;

__device__ __forceinline__ unsigned short f2bf(float f) {
  unsigned int u = __builtin_bit_cast(unsigned int, f);
  u += 0x7FFFu + ((u >> 16) & 1u);            // RTNE
  return (unsigned short)(u >> 16);
}

__device__ __forceinline__ unsigned int cvt_pk_bf16(float lo, float hi) {
  unsigned int w;
  asm("v_cvt_pk_bf16_f32 %0, %1, %2" : "=v"(w) : "v"(lo), "v"(hi));
  return w;
}

// bare v_exp_f32 — inputs are in [-12, 12], no denormal handling needed
__device__ __forceinline__ float fexp2(float x) {
#if __has_builtin(__builtin_amdgcn_exp2f)
  return __builtin_amdgcn_exp2f(x);
#else
  return exp2f(x);
#endif
}

__device__ __forceinline__ void gload_lds16(const void* g, void* lds) {
  __builtin_amdgcn_global_load_lds(
      (const __attribute__((address_space(1))) unsigned int*)g,
      (__attribute__((address_space(3))) unsigned int*)lds, 16, 0, 0);
}

// ---------------------------------------------------------------- pack weights fp32->bf16
__global__ __launch_bounds__(256) void pack_w_kernel(
    const float* __restrict__ w1, const float* __restrict__ w2,
    unsigned short* __restrict__ w1b, unsigned short* __restrict__ w2b) {
  const size_t W14 = (size_t)3 * CDIM * CDIM / 4;   // 786432 float4 groups
  const size_t W24 = (size_t)CDIM * CDIM / 4;       // 262144
  size_t i = (size_t)blockIdx.x * blockDim.x + threadIdx.x;
  const float* src; unsigned short* dst; size_t off;
  if (i < W14)             { src = w1; dst = w1b; off = i; }
  else if (i < W14 + W24)  { src = w2; dst = w2b; off = i - W14; }
  else return;
  float4 v = reinterpret_cast<const float4*>(src)[off];
  ushort4 u;
  u.x = f2bf(v.x); u.y = f2bf(v.y); u.z = f2bf(v.z); u.w = f2bf(v.w);
  reinterpret_cast<ushort4*>(dst)[off] = u;
}

// ---------------------------------------------------------------- QKV GEMM: fp32-A reg-staging (fused x cvt) + RMS-norm epilogue
// A = x fp32 [N][C]; B = Wqkv bf16-packed [3C][C]. A-tile conversion fused
// into staging: load 2x float4 (pre-swizzled source), cvt_pk, ds_write_b128.
__global__ __launch_bounds__(256, 3) void gemm_qkv_kernel(
    const float* __restrict__ Xf, const unsigned short* __restrict__ Bw,
    const float* __restrict__ bias, const float* __restrict__ qg,
    const float* __restrict__ kg, unsigned short* __restrict__ Qn,
    unsigned short* __restrict__ Kn, unsigned short* __restrict__ Vt) {
  __shared__ alignas(16) char As[128 * 128];
  __shared__ alignas(16) char Bs[128 * 128];
  const int t = threadIdx.x;
  const int lane = t & 63, wave = t >> 6;
  const int wr = wave >> 1, wc = wave & 1;
  const int lrow = lane & 15, lk = lane >> 4;
  const int row0 = blockIdx.x * 128, col0 = blockIdx.y * 128;
  const int K = CDIM;
  const f32x4 fzero = {0.f, 0.f, 0.f, 0.f};

  f32x4 acc[4][4];
#pragma unroll
  for (int m = 0; m < 4; ++m)
#pragma unroll
    for (int n = 0; n < 4; ++n) acc[m][n] = fzero;

  const int p_row = (t * 16) >> 7;
  const int p_cb  = (t * 16) & 127;
  // (c*32+p_row)&7 == p_row&7  ->  swizzle byte is c-invariant
  const int kb = p_cb ^ ((p_row & 7) << 4);

  // A fp32 source base (bf16-byte kb -> fp32-byte kb*2); c stride 32 rows
  const char* gA = (const char*)Xf + ((size_t)(row0 + p_row) * CDIM) * 4 + kb * 2;
  const char* gB = (const char*)Bw + ((size_t)(col0 + p_row) * K) * 2 + kb;

  f32x4 ra[4][2];
  auto loadA = [&](int kt) {
#pragma unroll
    for (int c = 0; c < 4; ++c) {
      const char* p = gA + (size_t)c * (32 * CDIM * 4) + kt * 4;
      ra[c][0] = *reinterpret_cast<const f32x4*>(p);
      ra[c][1] = *reinterpret_cast<const f32x4*>(p + 16);
    }
  };
  auto writeA = [&]() {
#pragma unroll
    for (int c = 0; c < 4; ++c) {
      u32x4 w;
      w[0] = cvt_pk_bf16(ra[c][0][0], ra[c][0][1]);
      w[1] = cvt_pk_bf16(ra[c][0][2], ra[c][0][3]);
      w[2] = cvt_pk_bf16(ra[c][1][0], ra[c][1][1]);
      w[3] = cvt_pk_bf16(ra[c][1][2], ra[c][1][3]);
      *reinterpret_cast<u32x4*>(As + c * 4096 + t * 16) = w;
    }
  };

  loadA(0);
  for (int kt = 0; kt < K; kt += 64) {
    __syncthreads();
    writeA();
#pragma unroll
    for (int c = 0; c < 4; ++c)
      gload_lds16(gB + (size_t)c * (32 * K * 2) + kt * 2, Bs + c * 4096 + wave * 1024);
    if (kt + 64 < K) loadA(kt + 64);
    __syncthreads();
#pragma unroll
    for (int kk = 0; kk < 2; ++kk) {
      bf16x8 a[4], b[4];
#pragma unroll
      for (int m = 0; m < 4; ++m) {
        int r = wr * 64 + m * 16 + lrow;
        a[m] = *reinterpret_cast<const bf16x8*>(
            As + r * 128 + ((kk * 64 + lk * 16) ^ ((r & 7) << 4)));
      }
#pragma unroll
      for (int n = 0; n < 4; ++n) {
        int r = wc * 64 + n * 16 + lrow;
        b[n] = *reinterpret_cast<const bf16x8*>(
            Bs + r * 128 + ((kk * 64 + lk * 16) ^ ((r & 7) << 4)));
      }
#pragma unroll
      for (int m = 0; m < 4; ++m)
#pragma unroll
        for (int n = 0; n < 4; ++n)
          acc[m][n] = __builtin_amdgcn_mfma_f32_16x16x32_bf16(a[m], b[n], acc[m][n], 0, 0, 0);
    }
  }

  // ---- fused epilogue ----
  const int typ  = col0 >> 10;                       // 0=q 1=k 2=v (block-uniform)
  const int hloc = (((col0 & 1023) >> 6) + wc) & 15; // head for this wave
  float bv[4];
#pragma unroll
  for (int n = 0; n < 4; ++n) bv[n] = bias[col0 + wc * 64 + n * 16 + lrow];

  if (typ == 2) {
#pragma unroll
    for (int m = 0; m < 4; ++m)
#pragma unroll
      for (int j = 0; j < 4; ++j) {
        int row = row0 + wr * 64 + m * 16 + lk * 4 + j;
        int np = (row & ~12) | ((row & 4) << 1) | ((row & 8) >> 1);
#pragma unroll
        for (int n = 0; n < 4; ++n) {
          int d = n * 16 + lrow;
          Vt[(size_t)(hloc * HD + d) * N_TOK + np] = f2bf(acc[m][n][j] + bv[n]);
        }
      }
  } else {
    const float* g = (typ == 0) ? qg : kg;
    const float gscale = (typ == 0) ? 1.0f : KSCALE;
    unsigned short* dst = (typ == 0) ? Qn : Kn;
    float gv[4];
#pragma unroll
    for (int n = 0; n < 4; ++n)
      gv[n] = g[hloc * HD + n * 16 + lrow] * gscale;
#pragma unroll
    for (int m = 0; m < 4; ++m)
#pragma unroll
      for (int j = 0; j < 4; ++j) {
        float tv[4];
        float ss = 0.f;
#pragma unroll
        for (int n = 0; n < 4; ++n) {
          tv[n] = acc[m][n][j] + bv[n];
          ss += tv[n] * tv[n];
        }
        ss += __shfl_xor(ss, 1);
        ss += __shfl_xor(ss, 2);
        ss += __shfl_xor(ss, 4);
        ss += __shfl_xor(ss, 8);
        float r = rsqrtf(fmaxf(ss, 1e-24f));
        int row = row0 + wr * 64 + m * 16 + lk * 4 + j;
#pragma unroll
        for (int n = 0; n < 4; ++n)
          dst[((size_t)hloc * N_TOK + row) * HD + n * 16 + lrow] =
              f2bf(tv[n] * r * gv[n]);
      }
  }
}

// ---------------------------------------------------------------- flash attention v12 (unchanged; best measured 78.4us)
__global__ __launch_bounds__(256, 4) void flash_kernel(
    const unsigned short* __restrict__ Qn, const unsigned short* __restrict__ Kn,
    const unsigned short* __restrict__ Vt, unsigned short* __restrict__ Opb,
    float* __restrict__ Lp) {
  __shared__ alignas(16) char Ks[2][64 * 128];
  __shared__ alignas(16) char Vs[2][64 * 128];
  const int t = threadIdx.x, lane = t & 63, wave = t >> 6;
  const int q = lane & 31, hi = lane >> 5;
  const int b = blockIdx.x;
  const int xcd = b & 7, idx = b >> 3;
  const int combo = xcd * 4 + (idx >> 5);   // 0..31
  const int qt = idx & 31;
  const int h = combo & 15;
  const int half = combo >> 4;
  const int q0 = qt * 128 + wave * 32;
  const int kv0 = half << 11;

  bf16x8 bq[4];
#pragma unroll
  for (int c = 0; c < 4; ++c)
    bq[c] = *reinterpret_cast<const bf16x8*>(
        Qn + ((size_t)h * N_TOK + q0 + q) * HD + c * 16 + hi * 8);

  f32x16 ot0, ot1;
#pragma unroll
  for (int r = 0; r < 16; ++r) { ot0[r] = 0.f; ot1[r] = 0.f; }
  f32x2 l2 = {0.f, 0.f};

  int koff[4], voff[4];
#pragma unroll
  for (int c = 0; c < 4; ++c)
    koff[c] = q * 128 + ((c * 32 + hi * 16) ^ ((q & 7) << 4));
#pragma unroll
  for (int kt = 0; kt < 4; ++kt)
    voff[kt] = q * 128 + ((kt * 32 + hi * 16) ^ ((q & 7) << 4));

  const int p_row = (t * 16) >> 7;
  const int p_cb  = (t * 16) & 127;
  const int scb   = p_cb ^ ((p_row & 7) << 4);
  const char* gK0 = (const char*)Kn + ((size_t)h * N_TOK + kv0 + p_row) * 128 + scb;
  const char* gK1 = gK0 + 32 * 128;
  const char* gV0 = (const char*)Vt + ((size_t)(h * HD + p_row) * N_TOK + kv0) * 2 + scb;
  const char* gV1 = gV0 + (size_t)32 * N_TOK * 2;

  u32x4 rK0, rK1, rV0, rV1;
  auto load_regs = [&]() {
    rK0 = *reinterpret_cast<const u32x4*>(gK0);
    rK1 = *reinterpret_cast<const u32x4*>(gK1);
    rV0 = *reinterpret_cast<const u32x4*>(gV0);
    rV1 = *reinterpret_cast<const u32x4*>(gV1);
    gK0 += 8192; gK1 += 8192; gV0 += 128; gV1 += 128;
  };
  auto write_lds = [&](int bb) {
    *reinterpret_cast<u32x4*>(Ks[bb] + t * 16)        = rK0;
    *reinterpret_cast<u32x4*>(Ks[bb] + 4096 + t * 16) = rK1;
    *reinterpret_cast<u32x4*>(Vs[bb] + t * 16)        = rV0;
    *reinterpret_cast<u32x4*>(Vs[bb] + 4096 + t * 16) = rV1;
  };

  load_regs();
  write_lds(0);
  __syncthreads();
  int buf = 0;

  for (int kv = kv0; kv < kv0 + 2048; kv += 64) {
    const bool more = (kv + 64 < kv0 + 2048);
    if (more) load_regs();

    const char* Kb = Ks[buf];
    const char* Vb = Vs[buf];

    f32x16 s0, s1;
#pragma unroll
    for (int r = 0; r < 16; ++r) { s0[r] = 0.f; s1[r] = 0.f; }
    __builtin_amdgcn_s_setprio(1);
#pragma unroll
    for (int c = 0; c < 4; ++c) {
      bf16x8 kf = *reinterpret_cast<const bf16x8*>(Kb + koff[c]);
      s0 = __builtin_amdgcn_mfma_f32_32x32x16_bf16(kf, bq[c], s0, 0, 0, 0);
    }
#pragma unroll
    for (int c = 0; c < 4; ++c) {
      bf16x8 kf = *reinterpret_cast<const bf16x8*>(Kb + koff[c] + 4096);
      s1 = __builtin_amdgcn_mfma_f32_32x32x16_bf16(kf, bq[c], s1, 0, 0, 0);
    }
    __builtin_amdgcn_s_setprio(0);

    unsigned int W0[8];
#pragma unroll
    for (int i = 0; i < 8; ++i) {
      float p0 = fexp2(s0[2 * i]);
      float p1 = fexp2(s0[2 * i + 1]);
      W0[i] = cvt_pk_bf16(p0, p1);
      l2 += (f32x2){p0, p1};
    }

    __builtin_amdgcn_s_setprio(1);
#pragma unroll
    for (int ktl = 0; ktl < 2; ++ktl) {
      u32x4 pw;
#pragma unroll
      for (int i = 0; i < 4; ++i) pw[i] = W0[ktl * 4 + i];
      bf16x8 pfrag = __builtin_bit_cast(bf16x8, pw);
      bf16x8 vf0 = *reinterpret_cast<const bf16x8*>(Vb + voff[ktl]);
      ot0 = __builtin_amdgcn_mfma_f32_32x32x16_bf16(vf0, pfrag, ot0, 0, 0, 0);
      bf16x8 vf1 = *reinterpret_cast<const bf16x8*>(Vb + voff[ktl] + 4096);
      ot1 = __builtin_amdgcn_mfma_f32_32x32x16_bf16(vf1, pfrag, ot1, 0, 0, 0);
    }
    __builtin_amdgcn_s_setprio(0);

    unsigned int W1[8];
#pragma unroll
    for (int i = 0; i < 8; ++i) {
      float p0 = fexp2(s1[2 * i]);
      float p1 = fexp2(s1[2 * i + 1]);
      W1[i] = cvt_pk_bf16(p0, p1);
      l2 += (f32x2){p0, p1};
    }

    __builtin_amdgcn_s_setprio(1);
#pragma unroll
    for (int ktl = 0; ktl < 2; ++ktl) {
      u32x4 pw;
#pragma unroll
      for (int i = 0; i < 4; ++i) pw[i] = W1[ktl * 4 + i];
      bf16x8 pfrag = __builtin_bit_cast(bf16x8, pw);
      bf16x8 vf0 = *reinterpret_cast<const bf16x8*>(Vb + voff[2 + ktl]);
      ot0 = __builtin_amdgcn_mfma_f32_32x32x16_bf16(vf0, pfrag, ot0, 0, 0, 0);
      bf16x8 vf1 = *reinterpret_cast<const bf16x8*>(Vb + voff[2 + ktl] + 4096);
      ot1 = __builtin_amdgcn_mfma_f32_32x32x16_bf16(vf1, pfrag, ot1, 0, 0, 0);
    }
    __builtin_amdgcn_s_setprio(0);

    if (more) {
      write_lds(buf ^ 1);
      __syncthreads();
      buf ^= 1;
    }
  }

  unsigned short* ob = Opb + ((size_t)half * N_TOK + q0 + q) * CDIM + h * HD;
#pragma unroll
  for (int g = 0; g < 4; ++g) {
    uint2 w;
    w.x = cvt_pk_bf16(ot0[4 * g + 0], ot0[4 * g + 1]);
    w.y = cvt_pk_bf16(ot0[4 * g + 2], ot0[4 * g + 3]);
    *reinterpret_cast<uint2*>(ob + g * 8 + hi * 4) = w;
    w.x = cvt_pk_bf16(ot1[4 * g + 0], ot1[4 * g + 1]);
    w.y = cvt_pk_bf16(ot1[4 * g + 2], ot1[4 * g + 3]);
    *reinterpret_cast<uint2*>(ob + 32 + g * 8 + hi * 4) = w;
  }
  float l = l2[0] + l2[1];
  l += __shfl_xor(l, 32);
  if (hi == 0)
    Lp[((size_t)half * NH + h) * N_TOK + q0 + q] = l;
}

// ---------------------------------------------------------------- output GEMM with fused combine in A-staging
// A = (Opb[0] + Opb[1]) / (l0+l1) as bf16, built on the fly per K-tile
// (each 64-col K-tile = exactly one head -> one rl scalar per row).
__global__ __launch_bounds__(256, 3) void gemm_out_kernel(
    const unsigned short* __restrict__ Opb, const float* __restrict__ Lp,
    const unsigned short* __restrict__ Bw, const float* __restrict__ bias,
    float* __restrict__ C) {
  __shared__ alignas(16) char As[128 * 128];
  __shared__ alignas(16) char Bs[128 * 128];
  const int t = threadIdx.x;
  const int lane = t & 63, wave = t >> 6;
  const int wr = wave >> 1, wc = wave & 1;
  const int lrow = lane & 15, lk = lane >> 4;
  const int row0 = blockIdx.x * 128, col0 = blockIdx.y * 128;
  const int K = CDIM;
  const f32x4 fzero = {0.f, 0.f, 0.f, 0.f};

  f32x4 acc[4][4];
#pragma unroll
  for (int m = 0; m < 4; ++m)
#pragma unroll
    for (int n = 0; n < 4; ++n) acc[m][n] = fzero;

  const int p_row = (t * 16) >> 7;
  const int p_cb  = (t * 16) & 127;
  const int kb = p_cb ^ ((p_row & 7) << 4);

  const char* gA0 = (const char*)Opb + ((size_t)(row0 + p_row) * CDIM) * 2 + kb;
  const char* gA1 = gA0 + (size_t)N_TOK * CDIM * 2;
  const char* gB  = (const char*)Bw + ((size_t)(col0 + p_row) * K) * 2 + kb;

  u32x4 ra0[4], ra1[4];
  float rl[4];
  auto loadA = [&](int kt) {
    int hh = kt >> 6;
#pragma unroll
    for (int c = 0; c < 4; ++c) {
      const char* p0 = gA0 + (size_t)c * (32 * CDIM * 2) + kt * 2;
      ra0[c] = *reinterpret_cast<const u32x4*>(p0);
      ra1[c] = *reinterpret_cast<const u32x4*>(gA1 + (size_t)c * (32 * CDIM * 2) + kt * 2);
      int n = row0 + c * 32 + p_row;
      rl[c] = 1.0f / (Lp[(size_t)hh * N_TOK + n] + Lp[((size_t)NH + hh) * N_TOK + n]);
    }
  };
  auto writeA = [&]() {
#pragma unroll
    for (int c = 0; c < 4; ++c) {
      u32x4 w;
#pragma unroll
      for (int j = 0; j < 4; ++j) {
        float a_lo = __builtin_bit_cast(float, ra0[c][j] << 16);
        float a_hi = __builtin_bit_cast(float, ra0[c][j] & 0xFFFF0000u);
        float b_lo = __builtin_bit_cast(float, ra1[c][j] << 16);
        float b_hi = __builtin_bit_cast(float, ra1[c][j] & 0xFFFF0000u);
        w[j] = cvt_pk_bf16((a_lo + b_lo) * rl[c], (a_hi + b_hi) * rl[c]);
      }
      *reinterpret_cast<u32x4*>(As + c * 4096 + t * 16) = w;
    }
  };

  loadA(0);
  for (int kt = 0; kt < K; kt += 64) {
    __syncthreads();
    writeA();
#pragma unroll
    for (int c = 0; c < 4; ++c)
      gload_lds16(gB + (size_t)c * (32 * K * 2) + kt * 2, Bs + c * 4096 + wave * 1024);
    if (kt + 64 < K) loadA(kt + 64);
    __syncthreads();
#pragma unroll
    for (int kk = 0; kk < 2; ++kk) {
      bf16x8 a[4], b[4];
#pragma unroll
      for (int m = 0; m < 4; ++m) {
        int r = wr * 64 + m * 16 + lrow;
        a[m] = *reinterpret_cast<const bf16x8*>(
            As + r * 128 + ((kk * 64 + lk * 16) ^ ((r & 7) << 4)));
      }
#pragma unroll
      for (int n = 0; n < 4; ++n) {
        int r = wc * 64 + n * 16 + lrow;
        b[n] = *reinterpret_cast<const bf16x8*>(
            Bs + r * 128 + ((kk * 64 + lk * 16) ^ ((r & 7) << 4)));
      }
#pragma unroll
      for (int m = 0; m < 4; ++m)
#pragma unroll
        for (int n = 0; n < 4; ++n)
          acc[m][n] = __builtin_amdgcn_mfma_f32_16x16x32_bf16(a[m], b[n], acc[m][n], 0, 0, 0);
    }
  }

#pragma unroll
  for (int m = 0; m < 4; ++m) {
    int row = row0 + wr * 64 + m * 16 + lk * 4;
#pragma unroll
    for (int n = 0; n < 4; ++n) {
      int col = col0 + wc * 64 + n * 16 + lrow;
      float bv = bias[col];
#pragma unroll
      for (int j = 0; j < 4; ++j)
        C[(size_t)(row + j) * CDIM + col] = acc[m][n][j] + bv;
    }
  }
}

// ---------------------------------------------------------------- launch
extern "C" void kernel_launch(void* const* d_in, const int* in_sizes, int n_in,
                              void* d_out, int out_size, void* d_ws, size_t ws_size,
                              hipStream_t stream) {
  const float* x    = (const float*)d_in[0];
  const float* Wqkv = (const float*)d_in[1];
  const float* bqkv = (const float*)d_in[2];
  const float* qg   = (const float*)d_in[3];
  const float* kg   = (const float*)d_in[4];
  const float* Wout = (const float*)d_in[5];
  const float* bout = (const float*)d_in[6];
  float* out = (float*)d_out;

  char* ws = (char*)d_ws;
  unsigned short* w1b = (unsigned short*)(ws);                       // 6MB
  unsigned short* w2b = (unsigned short*)(ws + ((size_t)8  << 20));  // 2MB
  unsigned short* Opb = (unsigned short*)(ws + ((size_t)16 << 20));  // 16MB bf16 partials
  float*          Lp  = (float*)         (ws + ((size_t)48 << 20));  // 0.5MB
  unsigned short* Qn  = (unsigned short*)(ws + ((size_t)64 << 20));
  unsigned short* Kn  = (unsigned short*)(ws + ((size_t)72 << 20));
  unsigned short* Vt  = (unsigned short*)(ws + ((size_t)80 << 20));

  pack_w_kernel<<<4096, 256, 0, stream>>>(Wqkv, Wout, w1b, w2b);
  gemm_qkv_kernel<<<dim3(32, 24), 256, 0, stream>>>(x, w1b, bqkv, qg, kg,
                                                    Qn, Kn, Vt);
  flash_kernel<<<1024, 256, 0, stream>>>(Qn, Kn, Vt, Opb, Lp);
  gemm_out_kernel<<<dim3(32, 8), 256, 0, stream>>>(Opb, Lp, w2b, bout, out);
}

// Round 14
// 150.270 us; speedup vs baseline: 1.0166x; 1.0166x over previous
//
#include <hip/hip_runtime.h>
#include <math.h>

#define N_TOK 4096
#define CDIM  1024
#define NH    16
#define HD    64

// scores: |q̂γ · k̂γ√D| <= 8 (γ=1), folded to log2 domain via K scale.
#define KSCALE 11.5416469f   // 8 * log2(e)

typedef __attribute__((ext_vector_type(8)))  __bf16 bf16x8;
typedef __attribute__((ext_vector_type(2)))  float  f32x2;
typedef __attribute__((ext_vector_type(4)))  float  f32x4;
typedef __attribute__((ext_vector_type(16))) float  f32x16;
typedef __attribute__((ext_vector_type(4)))  unsigned int u32x4;

__device__ __forceinline__ unsigned short f2bf(float f) {
  unsigned int u = __builtin_bit_cast(unsigned int, f);
  u += 0x7FFFu + ((u >> 16) & 1u);            // RTNE
  return (unsigned short)(u >> 16);
}

__device__ __forceinline__ unsigned int cvt_pk_bf16(float lo, float hi) {
  unsigned int w;
  asm("v_cvt_pk_bf16_f32 %0, %1, %2" : "=v"(w) : "v"(lo), "v"(hi));
  return w;
}

// bare v_exp_f32 — inputs are in [-12, 12], no denormal handling needed
__device__ __forceinline__ float fexp2(float x) {
#if __has_builtin(__builtin_amdgcn_exp2f)
  return __builtin_amdgcn_exp2f(x);
#else
  return exp2f(x);
#endif
}

__device__ __forceinline__ void gload_lds16(const void* g, void* lds) {
  __builtin_amdgcn_global_load_lds(
      (const __attribute__((address_space(1))) unsigned int*)g,
      (__attribute__((address_space(3))) unsigned int*)lds, 16, 0, 0);
}

// ---------------------------------------------------------------- pack fp32->bf16 (x + both weights)
__global__ __launch_bounds__(256) void pack_bf16_kernel(
    const float* __restrict__ x, const float* __restrict__ w1,
    const float* __restrict__ w2, unsigned short* __restrict__ xb,
    unsigned short* __restrict__ w1b, unsigned short* __restrict__ w2b) {
  const size_t X4 = (size_t)N_TOK * CDIM / 4;
  const size_t W14 = (size_t)3 * CDIM * CDIM / 4;
  const size_t W24 = (size_t)CDIM * CDIM / 4;
  size_t i = (size_t)blockIdx.x * blockDim.x + threadIdx.x;
  const float* src; unsigned short* dst; size_t off;
  if (i < X4)              { src = x;  dst = xb;  off = i; }
  else if (i < X4 + W14)   { src = w1; dst = w1b; off = i - X4; }
  else if (i < X4 + W14 + W24) { src = w2; dst = w2b; off = i - X4 - W14; }
  else return;
  float4 v = reinterpret_cast<const float4*>(src)[off];
  ushort4 u;
  u.x = f2bf(v.x); u.y = f2bf(v.y); u.z = f2bf(v.z); u.w = f2bf(v.w);
  reinterpret_cast<ushort4*>(dst)[off] = u;
}

// ---------------------------------------------------------------- QKV GEMM (gload_lds both operands) + fused RMS-norm epilogue
__global__ __launch_bounds__(256, 2) void gemm_qkv_kernel(
    const unsigned short* __restrict__ A, const unsigned short* __restrict__ B,
    const float* __restrict__ bias, const float* __restrict__ qg,
    const float* __restrict__ kg, unsigned short* __restrict__ Qn,
    unsigned short* __restrict__ Kn, unsigned short* __restrict__ Vt) {
  __shared__ alignas(16) char As[128 * 128];
  __shared__ alignas(16) char Bs[128 * 128];
  const int t = threadIdx.x;
  const int lane = t & 63, wave = t >> 6;
  const int wr = wave >> 1, wc = wave & 1;
  const int lrow = lane & 15, lk = lane >> 4;
  const int row0 = blockIdx.x * 128, col0 = blockIdx.y * 128;
  const int K = CDIM;
  const f32x4 fzero = {0.f, 0.f, 0.f, 0.f};

  f32x4 acc[4][4];
#pragma unroll
  for (int m = 0; m < 4; ++m)
#pragma unroll
    for (int n = 0; n < 4; ++n) acc[m][n] = fzero;

  const int p_row = (t * 16) >> 7;
  const int p_cb  = (t * 16) & 127;

  for (int kt = 0; kt < K; kt += 64) {
    __syncthreads();
#pragma unroll
    for (int c = 0; c < 4; ++c) {
      int row = c * 32 + p_row;
      int kb = p_cb ^ ((row & 7) << 4);
      const char* gA = (const char*)A + ((size_t)(row0 + row) * K + kt) * 2 + kb;
      const char* gB = (const char*)B + ((size_t)(col0 + row) * K + kt) * 2 + kb;
      gload_lds16(gA, As + c * 4096 + wave * 1024);
      gload_lds16(gB, Bs + c * 4096 + wave * 1024);
    }
    __syncthreads();
#pragma unroll
    for (int kk = 0; kk < 2; ++kk) {
      bf16x8 a[4], b[4];
#pragma unroll
      for (int m = 0; m < 4; ++m) {
        int r = wr * 64 + m * 16 + lrow;
        a[m] = *reinterpret_cast<const bf16x8*>(
            As + r * 128 + ((kk * 64 + lk * 16) ^ ((r & 7) << 4)));
      }
#pragma unroll
      for (int n = 0; n < 4; ++n) {
        int r = wc * 64 + n * 16 + lrow;
        b[n] = *reinterpret_cast<const bf16x8*>(
            Bs + r * 128 + ((kk * 64 + lk * 16) ^ ((r & 7) << 4)));
      }
#pragma unroll
      for (int m = 0; m < 4; ++m)
#pragma unroll
        for (int n = 0; n < 4; ++n)
          acc[m][n] = __builtin_amdgcn_mfma_f32_16x16x32_bf16(a[m], b[n], acc[m][n], 0, 0, 0);
    }
  }

  // ---- fused epilogue ----
  const int typ  = col0 >> 10;                       // 0=q 1=k 2=v (block-uniform)
  const int hloc = (((col0 & 1023) >> 6) + wc) & 15; // head for this wave
  float bv[4];
#pragma unroll
  for (int n = 0; n < 4; ++n) bv[n] = bias[col0 + wc * 64 + n * 16 + lrow];

  if (typ == 2) {
#pragma unroll
    for (int m = 0; m < 4; ++m)
#pragma unroll
      for (int j = 0; j < 4; ++j) {
        int row = row0 + wr * 64 + m * 16 + lk * 4 + j;
        int np = (row & ~12) | ((row & 4) << 1) | ((row & 8) >> 1);
#pragma unroll
        for (int n = 0; n < 4; ++n) {
          int d = n * 16 + lrow;
          Vt[(size_t)(hloc * HD + d) * N_TOK + np] = f2bf(acc[m][n][j] + bv[n]);
        }
      }
  } else {
    const float* g = (typ == 0) ? qg : kg;
    const float gscale = (typ == 0) ? 1.0f : KSCALE;
    unsigned short* dst = (typ == 0) ? Qn : Kn;
    float gv[4];
#pragma unroll
    for (int n = 0; n < 4; ++n)
      gv[n] = g[hloc * HD + n * 16 + lrow] * gscale;
#pragma unroll
    for (int m = 0; m < 4; ++m)
#pragma unroll
      for (int j = 0; j < 4; ++j) {
        float tv[4];
        float ss = 0.f;
#pragma unroll
        for (int n = 0; n < 4; ++n) {
          tv[n] = acc[m][n][j] + bv[n];
          ss += tv[n] * tv[n];
        }
        ss += __shfl_xor(ss, 1);
        ss += __shfl_xor(ss, 2);
        ss += __shfl_xor(ss, 4);
        ss += __shfl_xor(ss, 8);
        float r = rsqrtf(fmaxf(ss, 1e-24f));
        int row = row0 + wr * 64 + m * 16 + lk * 4 + j;
#pragma unroll
        for (int n = 0; n < 4; ++n)
          dst[((size_t)hloc * N_TOK + row) * HD + n * 16 + lrow] =
              f2bf(tv[n] * r * gv[n]);
      }
  }
}

// ---------------------------------------------------------------- flash attention v12 (unchanged; best measured 78.4us)
__global__ __launch_bounds__(256, 4) void flash_kernel(
    const unsigned short* __restrict__ Qn, const unsigned short* __restrict__ Kn,
    const unsigned short* __restrict__ Vt, unsigned short* __restrict__ Opb,
    float* __restrict__ Lp) {
  __shared__ alignas(16) char Ks[2][64 * 128];
  __shared__ alignas(16) char Vs[2][64 * 128];
  const int t = threadIdx.x, lane = t & 63, wave = t >> 6;
  const int q = lane & 31, hi = lane >> 5;
  const int b = blockIdx.x;
  const int xcd = b & 7, idx = b >> 3;
  const int combo = xcd * 4 + (idx >> 5);   // 0..31
  const int qt = idx & 31;
  const int h = combo & 15;
  const int half = combo >> 4;
  const int q0 = qt * 128 + wave * 32;
  const int kv0 = half << 11;

  bf16x8 bq[4];
#pragma unroll
  for (int c = 0; c < 4; ++c)
    bq[c] = *reinterpret_cast<const bf16x8*>(
        Qn + ((size_t)h * N_TOK + q0 + q) * HD + c * 16 + hi * 8);

  f32x16 ot0, ot1;
#pragma unroll
  for (int r = 0; r < 16; ++r) { ot0[r] = 0.f; ot1[r] = 0.f; }
  f32x2 l2 = {0.f, 0.f};

  int koff[4], voff[4];
#pragma unroll
  for (int c = 0; c < 4; ++c)
    koff[c] = q * 128 + ((c * 32 + hi * 16) ^ ((q & 7) << 4));
#pragma unroll
  for (int kt = 0; kt < 4; ++kt)
    voff[kt] = q * 128 + ((kt * 32 + hi * 16) ^ ((q & 7) << 4));

  const int p_row = (t * 16) >> 7;
  const int p_cb  = (t * 16) & 127;
  const int scb   = p_cb ^ ((p_row & 7) << 4);
  const char* gK0 = (const char*)Kn + ((size_t)h * N_TOK + kv0 + p_row) * 128 + scb;
  const char* gK1 = gK0 + 32 * 128;
  const char* gV0 = (const char*)Vt + ((size_t)(h * HD + p_row) * N_TOK + kv0) * 2 + scb;
  const char* gV1 = gV0 + (size_t)32 * N_TOK * 2;

  u32x4 rK0, rK1, rV0, rV1;
  auto load_regs = [&]() {
    rK0 = *reinterpret_cast<const u32x4*>(gK0);
    rK1 = *reinterpret_cast<const u32x4*>(gK1);
    rV0 = *reinterpret_cast<const u32x4*>(gV0);
    rV1 = *reinterpret_cast<const u32x4*>(gV1);
    gK0 += 8192; gK1 += 8192; gV0 += 128; gV1 += 128;
  };
  auto write_lds = [&](int bb) {
    *reinterpret_cast<u32x4*>(Ks[bb] + t * 16)        = rK0;
    *reinterpret_cast<u32x4*>(Ks[bb] + 4096 + t * 16) = rK1;
    *reinterpret_cast<u32x4*>(Vs[bb] + t * 16)        = rV0;
    *reinterpret_cast<u32x4*>(Vs[bb] + 4096 + t * 16) = rV1;
  };

  load_regs();
  write_lds(0);
  __syncthreads();
  int buf = 0;

  for (int kv = kv0; kv < kv0 + 2048; kv += 64) {
    const bool more = (kv + 64 < kv0 + 2048);
    if (more) load_regs();

    const char* Kb = Ks[buf];
    const char* Vb = Vs[buf];

    f32x16 s0, s1;
#pragma unroll
    for (int r = 0; r < 16; ++r) { s0[r] = 0.f; s1[r] = 0.f; }
    __builtin_amdgcn_s_setprio(1);
#pragma unroll
    for (int c = 0; c < 4; ++c) {
      bf16x8 kf = *reinterpret_cast<const bf16x8*>(Kb + koff[c]);
      s0 = __builtin_amdgcn_mfma_f32_32x32x16_bf16(kf, bq[c], s0, 0, 0, 0);
    }
#pragma unroll
    for (int c = 0; c < 4; ++c) {
      bf16x8 kf = *reinterpret_cast<const bf16x8*>(Kb + koff[c] + 4096);
      s1 = __builtin_amdgcn_mfma_f32_32x32x16_bf16(kf, bq[c], s1, 0, 0, 0);
    }
    __builtin_amdgcn_s_setprio(0);

    unsigned int W0[8];
#pragma unroll
    for (int i = 0; i < 8; ++i) {
      float p0 = fexp2(s0[2 * i]);
      float p1 = fexp2(s0[2 * i + 1]);
      W0[i] = cvt_pk_bf16(p0, p1);
      l2 += (f32x2){p0, p1};
    }

    __builtin_amdgcn_s_setprio(1);
#pragma unroll
    for (int ktl = 0; ktl < 2; ++ktl) {
      u32x4 pw;
#pragma unroll
      for (int i = 0; i < 4; ++i) pw[i] = W0[ktl * 4 + i];
      bf16x8 pfrag = __builtin_bit_cast(bf16x8, pw);
      bf16x8 vf0 = *reinterpret_cast<const bf16x8*>(Vb + voff[ktl]);
      ot0 = __builtin_amdgcn_mfma_f32_32x32x16_bf16(vf0, pfrag, ot0, 0, 0, 0);
      bf16x8 vf1 = *reinterpret_cast<const bf16x8*>(Vb + voff[ktl] + 4096);
      ot1 = __builtin_amdgcn_mfma_f32_32x32x16_bf16(vf1, pfrag, ot1, 0, 0, 0);
    }
    __builtin_amdgcn_s_setprio(0);

    unsigned int W1[8];
#pragma unroll
    for (int i = 0; i < 8; ++i) {
      float p0 = fexp2(s1[2 * i]);
      float p1 = fexp2(s1[2 * i + 1]);
      W1[i] = cvt_pk_bf16(p0, p1);
      l2 += (f32x2){p0, p1};
    }

    __builtin_amdgcn_s_setprio(1);
#pragma unroll
    for (int ktl = 0; ktl < 2; ++ktl) {
      u32x4 pw;
#pragma unroll
      for (int i = 0; i < 4; ++i) pw[i] = W1[ktl * 4 + i];
      bf16x8 pfrag = __builtin_bit_cast(bf16x8, pw);
      bf16x8 vf0 = *reinterpret_cast<const bf16x8*>(Vb + voff[2 + ktl]);
      ot0 = __builtin_amdgcn_mfma_f32_32x32x16_bf16(vf0, pfrag, ot0, 0, 0, 0);
      bf16x8 vf1 = *reinterpret_cast<const bf16x8*>(Vb + voff[2 + ktl] + 4096);
      ot1 = __builtin_amdgcn_mfma_f32_32x32x16_bf16(vf1, pfrag, ot1, 0, 0, 0);
    }
    __builtin_amdgcn_s_setprio(0);

    if (more) {
      write_lds(buf ^ 1);
      __syncthreads();
      buf ^= 1;
    }
  }

  unsigned short* ob = Opb + ((size_t)half * N_TOK + q0 + q) * CDIM + h * HD;
#pragma unroll
  for (int g = 0; g < 4; ++g) {
    uint2 w;
    w.x = cvt_pk_bf16(ot0[4 * g + 0], ot0[4 * g + 1]);
    w.y = cvt_pk_bf16(ot0[4 * g + 2], ot0[4 * g + 3]);
    *reinterpret_cast<uint2*>(ob + g * 8 + hi * 4) = w;
    w.x = cvt_pk_bf16(ot1[4 * g + 0], ot1[4 * g + 1]);
    w.y = cvt_pk_bf16(ot1[4 * g + 2], ot1[4 * g + 3]);
    *reinterpret_cast<uint2*>(ob + 32 + g * 8 + hi * 4) = w;
  }
  float l = l2[0] + l2[1];
  l += __shfl_xor(l, 32);
  if (hi == 0)
    Lp[((size_t)half * NH + h) * N_TOK + q0 + q] = l;
}

// ---------------------------------------------------------------- output GEMM with fused combine in A-staging
// (reg-staging forced here: A = (Opb0+Opb1)*rl needs transformation; each
// 64-col K-tile = one head -> rl is a per-row scalar per tile)
__global__ __launch_bounds__(256, 2) void gemm_out_kernel(
    const unsigned short* __restrict__ Opb, const float* __restrict__ Lp,
    const unsigned short* __restrict__ Bw, const float* __restrict__ bias,
    float* __restrict__ C) {
  __shared__ alignas(16) char As[128 * 128];
  __shared__ alignas(16) char Bs[128 * 128];
  const int t = threadIdx.x;
  const int lane = t & 63, wave = t >> 6;
  const int wr = wave >> 1, wc = wave & 1;
  const int lrow = lane & 15, lk = lane >> 4;
  const int row0 = blockIdx.x * 128, col0 = blockIdx.y * 128;
  const int K = CDIM;
  const f32x4 fzero = {0.f, 0.f, 0.f, 0.f};

  f32x4 acc[4][4];
#pragma unroll
  for (int m = 0; m < 4; ++m)
#pragma unroll
    for (int n = 0; n < 4; ++n) acc[m][n] = fzero;

  const int p_row = (t * 16) >> 7;
  const int p_cb  = (t * 16) & 127;
  const int kb = p_cb ^ ((p_row & 7) << 4);

  const char* gA0 = (const char*)Opb + ((size_t)(row0 + p_row) * CDIM) * 2 + kb;
  const char* gA1 = gA0 + (size_t)N_TOK * CDIM * 2;
  const char* gB  = (const char*)Bw + ((size_t)(col0 + p_row) * K) * 2 + kb;

  u32x4 ra0[4], ra1[4];
  float rl[4];
  auto loadA = [&](int kt) {
    int hh = kt >> 6;
#pragma unroll
    for (int c = 0; c < 4; ++c) {
      ra0[c] = *reinterpret_cast<const u32x4*>(gA0 + (size_t)c * (32 * CDIM * 2) + kt * 2);
      ra1[c] = *reinterpret_cast<const u32x4*>(gA1 + (size_t)c * (32 * CDIM * 2) + kt * 2);
      int n = row0 + c * 32 + p_row;
      rl[c] = 1.0f / (Lp[(size_t)hh * N_TOK + n] + Lp[((size_t)NH + hh) * N_TOK + n]);
    }
  };
  auto writeA = [&]() {
#pragma unroll
    for (int c = 0; c < 4; ++c) {
      u32x4 w;
#pragma unroll
      for (int j = 0; j < 4; ++j) {
        float a_lo = __builtin_bit_cast(float, ra0[c][j] << 16);
        float a_hi = __builtin_bit_cast(float, ra0[c][j] & 0xFFFF0000u);
        float b_lo = __builtin_bit_cast(float, ra1[c][j] << 16);
        float b_hi = __builtin_bit_cast(float, ra1[c][j] & 0xFFFF0000u);
        w[j] = cvt_pk_bf16((a_lo + b_lo) * rl[c], (a_hi + b_hi) * rl[c]);
      }
      *reinterpret_cast<u32x4*>(As + c * 4096 + t * 16) = w;
    }
  };

  loadA(0);
  for (int kt = 0; kt < K; kt += 64) {
    __syncthreads();
    writeA();
#pragma unroll
    for (int c = 0; c < 4; ++c)
      gload_lds16(gB + (size_t)c * (32 * K * 2) + kt * 2, Bs + c * 4096 + wave * 1024);
    if (kt + 64 < K) loadA(kt + 64);
    __syncthreads();
#pragma unroll
    for (int kk = 0; kk < 2; ++kk) {
      bf16x8 a[4], b[4];
#pragma unroll
      for (int m = 0; m < 4; ++m) {
        int r = wr * 64 + m * 16 + lrow;
        a[m] = *reinterpret_cast<const bf16x8*>(
            As + r * 128 + ((kk * 64 + lk * 16) ^ ((r & 7) << 4)));
      }
#pragma unroll
      for (int n = 0; n < 4; ++n) {
        int r = wc * 64 + n * 16 + lrow;
        b[n] = *reinterpret_cast<const bf16x8*>(
            Bs + r * 128 + ((kk * 64 + lk * 16) ^ ((r & 7) << 4)));
      }
#pragma unroll
      for (int m = 0; m < 4; ++m)
#pragma unroll
        for (int n = 0; n < 4; ++n)
          acc[m][n] = __builtin_amdgcn_mfma_f32_16x16x32_bf16(a[m], b[n], acc[m][n], 0, 0, 0);
    }
  }

#pragma unroll
  for (int m = 0; m < 4; ++m) {
    int row = row0 + wr * 64 + m * 16 + lk * 4;
#pragma unroll
    for (int n = 0; n < 4; ++n) {
      int col = col0 + wc * 64 + n * 16 + lrow;
      float bv = bias[col];
#pragma unroll
      for (int j = 0; j < 4; ++j)
        C[(size_t)(row + j) * CDIM + col] = acc[m][n][j] + bv;
    }
  }
}

// ---------------------------------------------------------------- launch
extern "C" void kernel_launch(void* const* d_in, const int* in_sizes, int n_in,
                              void* d_out, int out_size, void* d_ws, size_t ws_size,
                              hipStream_t stream) {
  const float* x    = (const float*)d_in[0];
  const float* Wqkv = (const float*)d_in[1];
  const float* bqkv = (const float*)d_in[2];
  const float* qg   = (const float*)d_in[3];
  const float* kg   = (const float*)d_in[4];
  const float* Wout = (const float*)d_in[5];
  const float* bout = (const float*)d_in[6];
  float* out = (float*)d_out;

  char* ws = (char*)d_ws;
  unsigned short* xb  = (unsigned short*)(ws);                       // 8MB
  unsigned short* w1b = (unsigned short*)(ws + ((size_t)8  << 20));  // 6MB
  unsigned short* w2b = (unsigned short*)(ws + ((size_t)14 << 20));  // 2MB
  unsigned short* Opb = (unsigned short*)(ws + ((size_t)16 << 20));  // 16MB bf16 partials
  float*          Lp  = (float*)         (ws + ((size_t)48 << 20));  // 0.5MB
  unsigned short* Qn  = (unsigned short*)(ws + ((size_t)64 << 20));
  unsigned short* Kn  = (unsigned short*)(ws + ((size_t)72 << 20));
  unsigned short* Vt  = (unsigned short*)(ws + ((size_t)80 << 20));

  pack_bf16_kernel<<<8192, 256, 0, stream>>>(x, Wqkv, Wout, xb, w1b, w2b);
  gemm_qkv_kernel<<<dim3(32, 24), 256, 0, stream>>>(xb, w1b, bqkv, qg, kg,
                                                    Qn, Kn, Vt);
  flash_kernel<<<1024, 256, 0, stream>>>(Qn, Kn, Vt, Opb, Lp);
  gemm_out_kernel<<<dim3(32, 8), 256, 0, stream>>>(Opb, Lp, w2b, bout, out);
}

// Round 15
// 140.660 us; speedup vs baseline: 1.0860x; 1.0683x over previous
//
#include <hip/hip_runtime.h>
#include <math.h>

#define N_TOK 4096
#define CDIM  1024
#define NH    16
#define HD    64

// scores: |q̂γ · k̂γ√D| <= 8 (γ=1), folded to log2 domain via K scale.
#define KSCALE 11.5416469f   // 8 * log2(e)

typedef __attribute__((ext_vector_type(8)))  __bf16 bf16x8;
typedef __attribute__((ext_vector_type(2)))  float  f32x2;
typedef __attribute__((ext_vector_type(4)))  float  f32x4;
typedef __attribute__((ext_vector_type(16))) float  f32x16;
typedef __attribute__((ext_vector_type(4)))  unsigned int u32x4;

__device__ __forceinline__ unsigned short f2bf(float f) {
  unsigned int u = __builtin_bit_cast(unsigned int, f);
  u += 0x7FFFu + ((u >> 16) & 1u);            // RTNE
  return (unsigned short)(u >> 16);
}

__device__ __forceinline__ unsigned int cvt_pk_bf16(float lo, float hi) {
  unsigned int w;
  asm("v_cvt_pk_bf16_f32 %0, %1, %2" : "=v"(w) : "v"(lo), "v"(hi));
  return w;
}

// bare v_exp_f32 — inputs are in [-12, 12], no denormal handling needed
__device__ __forceinline__ float fexp2(float x) {
#if __has_builtin(__builtin_amdgcn_exp2f)
  return __builtin_amdgcn_exp2f(x);
#else
  return exp2f(x);
#endif
}

__device__ __forceinline__ void gload_lds16(const void* g, void* lds) {
  __builtin_amdgcn_global_load_lds(
      (const __attribute__((address_space(1))) unsigned int*)g,
      (__attribute__((address_space(3))) unsigned int*)lds, 16, 0, 0);
}

// ---------------------------------------------------------------- pack fp32->bf16
__global__ __launch_bounds__(256) void pack_bf16_kernel(
    const float* __restrict__ x, const float* __restrict__ w1,
    const float* __restrict__ w2, unsigned short* __restrict__ xb,
    unsigned short* __restrict__ w1b, unsigned short* __restrict__ w2b) {
  const size_t X4 = (size_t)N_TOK * CDIM / 4;
  const size_t W14 = (size_t)3 * CDIM * CDIM / 4;
  const size_t W24 = (size_t)CDIM * CDIM / 4;
  size_t i = (size_t)blockIdx.x * blockDim.x + threadIdx.x;
  const float* src; unsigned short* dst; size_t off;
  if (i < X4)              { src = x;  dst = xb;  off = i; }
  else if (i < X4 + W14)   { src = w1; dst = w1b; off = i - X4; }
  else if (i < X4 + W14 + W24) { src = w2; dst = w2b; off = i - X4 - W14; }
  else return;
  float4 v = reinterpret_cast<const float4*>(src)[off];
  ushort4 u;
  u.x = f2bf(v.x); u.y = f2bf(v.y); u.z = f2bf(v.z); u.w = f2bf(v.w);
  reinterpret_cast<ushort4*>(dst)[off] = u;
}

// ---------------------------------------------------------------- bf16 GEMM, C = A * B^T + bias (fp32 out)
__global__ __launch_bounds__(256, 2) void gemm_bt_kernel(
    const unsigned short* __restrict__ A, const unsigned short* __restrict__ B,
    const float* __restrict__ bias, float* __restrict__ C,
    int M, int Ncols, int K) {
  __shared__ alignas(16) char As[128 * 128];
  __shared__ alignas(16) char Bs[128 * 128];
  const int t = threadIdx.x;
  const int lane = t & 63, wave = t >> 6;
  const int wr = wave >> 1, wc = wave & 1;
  const int lrow = lane & 15, lk = lane >> 4;
  const int row0 = blockIdx.x * 128, col0 = blockIdx.y * 128;
  const f32x4 fzero = {0.f, 0.f, 0.f, 0.f};

  f32x4 acc[4][4];
#pragma unroll
  for (int m = 0; m < 4; ++m)
#pragma unroll
    for (int n = 0; n < 4; ++n) acc[m][n] = fzero;

  const int p_row = (t * 16) >> 7;
  const int p_cb  = (t * 16) & 127;

  for (int kt = 0; kt < K; kt += 64) {
    __syncthreads();
#pragma unroll
    for (int c = 0; c < 4; ++c) {
      int row = c * 32 + p_row;
      int kb = p_cb ^ ((row & 7) << 4);
      const char* gA = (const char*)A + ((size_t)(row0 + row) * K + kt) * 2 + kb;
      const char* gB = (const char*)B + ((size_t)(col0 + row) * K + kt) * 2 + kb;
      gload_lds16(gA, As + c * 4096 + wave * 1024);
      gload_lds16(gB, Bs + c * 4096 + wave * 1024);
    }
    __syncthreads();
#pragma unroll
    for (int kk = 0; kk < 2; ++kk) {
      bf16x8 a[4], b[4];
#pragma unroll
      for (int m = 0; m < 4; ++m) {
        int r = wr * 64 + m * 16 + lrow;
        a[m] = *reinterpret_cast<const bf16x8*>(
            As + r * 128 + ((kk * 64 + lk * 16) ^ ((r & 7) << 4)));
      }
#pragma unroll
      for (int n = 0; n < 4; ++n) {
        int r = wc * 64 + n * 16 + lrow;
        b[n] = *reinterpret_cast<const bf16x8*>(
            Bs + r * 128 + ((kk * 64 + lk * 16) ^ ((r & 7) << 4)));
      }
#pragma unroll
      for (int m = 0; m < 4; ++m)
#pragma unroll
        for (int n = 0; n < 4; ++n)
          acc[m][n] = __builtin_amdgcn_mfma_f32_16x16x32_bf16(a[m], b[n], acc[m][n], 0, 0, 0);
    }
  }

#pragma unroll
  for (int m = 0; m < 4; ++m) {
    int row = row0 + wr * 64 + m * 16 + lk * 4;
#pragma unroll
    for (int n = 0; n < 4; ++n) {
      int col = col0 + wc * 64 + n * 16 + lrow;
      float bv = bias[col];
#pragma unroll
      for (int j = 0; j < 4; ++j)
        C[(size_t)(row + j) * Ncols + col] = acc[m][n][j] + bv;
    }
  }
}

// ---------------------------------------------------------------- QKV GEMM with fused RMS-norm epilogue
__global__ __launch_bounds__(256, 2) void gemm_qkv_kernel(
    const unsigned short* __restrict__ A, const unsigned short* __restrict__ B,
    const float* __restrict__ bias, const float* __restrict__ qg,
    const float* __restrict__ kg, unsigned short* __restrict__ Qn,
    unsigned short* __restrict__ Kn, unsigned short* __restrict__ Vt) {
  __shared__ alignas(16) char As[128 * 128];
  __shared__ alignas(16) char Bs[128 * 128];
  const int t = threadIdx.x;
  const int lane = t & 63, wave = t >> 6;
  const int wr = wave >> 1, wc = wave & 1;
  const int lrow = lane & 15, lk = lane >> 4;
  const int row0 = blockIdx.x * 128, col0 = blockIdx.y * 128;
  const int K = CDIM;
  const f32x4 fzero = {0.f, 0.f, 0.f, 0.f};

  f32x4 acc[4][4];
#pragma unroll
  for (int m = 0; m < 4; ++m)
#pragma unroll
    for (int n = 0; n < 4; ++n) acc[m][n] = fzero;

  const int p_row = (t * 16) >> 7;
  const int p_cb  = (t * 16) & 127;

  for (int kt = 0; kt < K; kt += 64) {
    __syncthreads();
#pragma unroll
    for (int c = 0; c < 4; ++c) {
      int row = c * 32 + p_row;
      int kb = p_cb ^ ((row & 7) << 4);
      const char* gA = (const char*)A + ((size_t)(row0 + row) * K + kt) * 2 + kb;
      const char* gB = (const char*)B + ((size_t)(col0 + row) * K + kt) * 2 + kb;
      gload_lds16(gA, As + c * 4096 + wave * 1024);
      gload_lds16(gB, Bs + c * 4096 + wave * 1024);
    }
    __syncthreads();
#pragma unroll
    for (int kk = 0; kk < 2; ++kk) {
      bf16x8 a[4], b[4];
#pragma unroll
      for (int m = 0; m < 4; ++m) {
        int r = wr * 64 + m * 16 + lrow;
        a[m] = *reinterpret_cast<const bf16x8*>(
            As + r * 128 + ((kk * 64 + lk * 16) ^ ((r & 7) << 4)));
      }
#pragma unroll
      for (int n = 0; n < 4; ++n) {
        int r = wc * 64 + n * 16 + lrow;
        b[n] = *reinterpret_cast<const bf16x8*>(
            Bs + r * 128 + ((kk * 64 + lk * 16) ^ ((r & 7) << 4)));
      }
#pragma unroll
      for (int m = 0; m < 4; ++m)
#pragma unroll
        for (int n = 0; n < 4; ++n)
          acc[m][n] = __builtin_amdgcn_mfma_f32_16x16x32_bf16(a[m], b[n], acc[m][n], 0, 0, 0);
    }
  }

  // ---- fused epilogue ----
  const int typ  = col0 >> 10;                       // 0=q 1=k 2=v (block-uniform)
  const int hloc = (((col0 & 1023) >> 6) + wc) & 15; // head for this wave
  float bv[4];
#pragma unroll
  for (int n = 0; n < 4; ++n) bv[n] = bias[col0 + wc * 64 + n * 16 + lrow];

  if (typ == 2) {
#pragma unroll
    for (int m = 0; m < 4; ++m)
#pragma unroll
      for (int j = 0; j < 4; ++j) {
        int row = row0 + wr * 64 + m * 16 + lk * 4 + j;
        int np = (row & ~12) | ((row & 4) << 1) | ((row & 8) >> 1);
#pragma unroll
        for (int n = 0; n < 4; ++n) {
          int d = n * 16 + lrow;
          Vt[(size_t)(hloc * HD + d) * N_TOK + np] = f2bf(acc[m][n][j] + bv[n]);
        }
      }
  } else {
    const float* g = (typ == 0) ? qg : kg;
    const float gscale = (typ == 0) ? 1.0f : KSCALE;
    unsigned short* dst = (typ == 0) ? Qn : Kn;
    float gv[4];
#pragma unroll
    for (int n = 0; n < 4; ++n)
      gv[n] = g[hloc * HD + n * 16 + lrow] * gscale;
#pragma unroll
    for (int m = 0; m < 4; ++m)
#pragma unroll
      for (int j = 0; j < 4; ++j) {
        float tv[4];
        float ss = 0.f;
#pragma unroll
        for (int n = 0; n < 4; ++n) {
          tv[n] = acc[m][n][j] + bv[n];
          ss += tv[n] * tv[n];
        }
        ss += __shfl_xor(ss, 1);
        ss += __shfl_xor(ss, 2);
        ss += __shfl_xor(ss, 4);
        ss += __shfl_xor(ss, 8);
        float r = rsqrtf(fmaxf(ss, 1e-24f));
        int row = row0 + wr * 64 + m * 16 + lk * 4 + j;
#pragma unroll
        for (int n = 0; n < 4; ++n)
          dst[((size_t)hloc * N_TOK + row) * HD + n * 16 + lrow] =
              f2bf(tv[n] * r * gv[n]);
      }
  }
}

// ---------------------------------------------------------------- flash attention v12 (best measured: 78.4us)
__global__ __launch_bounds__(256, 4) void flash_kernel(
    const unsigned short* __restrict__ Qn, const unsigned short* __restrict__ Kn,
    const unsigned short* __restrict__ Vt, unsigned short* __restrict__ Opb,
    float* __restrict__ Lp) {
  __shared__ alignas(16) char Ks[2][64 * 128];
  __shared__ alignas(16) char Vs[2][64 * 128];
  const int t = threadIdx.x, lane = t & 63, wave = t >> 6;
  const int q = lane & 31, hi = lane >> 5;
  const int b = blockIdx.x;
  const int xcd = b & 7, idx = b >> 3;
  const int combo = xcd * 4 + (idx >> 5);   // 0..31
  const int qt = idx & 31;
  const int h = combo & 15;
  const int half = combo >> 4;
  const int q0 = qt * 128 + wave * 32;
  const int kv0 = half << 11;

  bf16x8 bq[4];
#pragma unroll
  for (int c = 0; c < 4; ++c)
    bq[c] = *reinterpret_cast<const bf16x8*>(
        Qn + ((size_t)h * N_TOK + q0 + q) * HD + c * 16 + hi * 8);

  f32x16 ot0, ot1;
#pragma unroll
  for (int r = 0; r < 16; ++r) { ot0[r] = 0.f; ot1[r] = 0.f; }
  f32x2 l2 = {0.f, 0.f};

  int koff[4], voff[4];
#pragma unroll
  for (int c = 0; c < 4; ++c)
    koff[c] = q * 128 + ((c * 32 + hi * 16) ^ ((q & 7) << 4));
#pragma unroll
  for (int kt = 0; kt < 4; ++kt)
    voff[kt] = q * 128 + ((kt * 32 + hi * 16) ^ ((q & 7) << 4));

  const int p_row = (t * 16) >> 7;
  const int p_cb  = (t * 16) & 127;
  const int scb   = p_cb ^ ((p_row & 7) << 4);
  const char* gK0 = (const char*)Kn + ((size_t)h * N_TOK + kv0 + p_row) * 128 + scb;
  const char* gK1 = gK0 + 32 * 128;
  const char* gV0 = (const char*)Vt + ((size_t)(h * HD + p_row) * N_TOK + kv0) * 2 + scb;
  const char* gV1 = gV0 + (size_t)32 * N_TOK * 2;

  u32x4 rK0, rK1, rV0, rV1;
  auto load_regs = [&]() {
    rK0 = *reinterpret_cast<const u32x4*>(gK0);
    rK1 = *reinterpret_cast<const u32x4*>(gK1);
    rV0 = *reinterpret_cast<const u32x4*>(gV0);
    rV1 = *reinterpret_cast<const u32x4*>(gV1);
    gK0 += 8192; gK1 += 8192; gV0 += 128; gV1 += 128;
  };
  auto write_lds = [&](int bb) {
    *reinterpret_cast<u32x4*>(Ks[bb] + t * 16)        = rK0;
    *reinterpret_cast<u32x4*>(Ks[bb] + 4096 + t * 16) = rK1;
    *reinterpret_cast<u32x4*>(Vs[bb] + t * 16)        = rV0;
    *reinterpret_cast<u32x4*>(Vs[bb] + 4096 + t * 16) = rV1;
  };

  load_regs();
  write_lds(0);
  __syncthreads();
  int buf = 0;

  for (int kv = kv0; kv < kv0 + 2048; kv += 64) {
    const bool more = (kv + 64 < kv0 + 2048);
    if (more) load_regs();

    const char* Kb = Ks[buf];
    const char* Vb = Vs[buf];

    f32x16 s0, s1;
#pragma unroll
    for (int r = 0; r < 16; ++r) { s0[r] = 0.f; s1[r] = 0.f; }
    __builtin_amdgcn_s_setprio(1);
#pragma unroll
    for (int c = 0; c < 4; ++c) {
      bf16x8 kf = *reinterpret_cast<const bf16x8*>(Kb + koff[c]);
      s0 = __builtin_amdgcn_mfma_f32_32x32x16_bf16(kf, bq[c], s0, 0, 0, 0);
    }
#pragma unroll
    for (int c = 0; c < 4; ++c) {
      bf16x8 kf = *reinterpret_cast<const bf16x8*>(Kb + koff[c] + 4096);
      s1 = __builtin_amdgcn_mfma_f32_32x32x16_bf16(kf, bq[c], s1, 0, 0, 0);
    }
    __builtin_amdgcn_s_setprio(0);

    unsigned int W0[8];
#pragma unroll
    for (int i = 0; i < 8; ++i) {
      float p0 = fexp2(s0[2 * i]);
      float p1 = fexp2(s0[2 * i + 1]);
      W0[i] = cvt_pk_bf16(p0, p1);
      l2 += (f32x2){p0, p1};
    }

    __builtin_amdgcn_s_setprio(1);
#pragma unroll
    for (int ktl = 0; ktl < 2; ++ktl) {
      u32x4 pw;
#pragma unroll
      for (int i = 0; i < 4; ++i) pw[i] = W0[ktl * 4 + i];
      bf16x8 pfrag = __builtin_bit_cast(bf16x8, pw);
      bf16x8 vf0 = *reinterpret_cast<const bf16x8*>(Vb + voff[ktl]);
      ot0 = __builtin_amdgcn_mfma_f32_32x32x16_bf16(vf0, pfrag, ot0, 0, 0, 0);
      bf16x8 vf1 = *reinterpret_cast<const bf16x8*>(Vb + voff[ktl] + 4096);
      ot1 = __builtin_amdgcn_mfma_f32_32x32x16_bf16(vf1, pfrag, ot1, 0, 0, 0);
    }
    __builtin_amdgcn_s_setprio(0);

    unsigned int W1[8];
#pragma unroll
    for (int i = 0; i < 8; ++i) {
      float p0 = fexp2(s1[2 * i]);
      float p1 = fexp2(s1[2 * i + 1]);
      W1[i] = cvt_pk_bf16(p0, p1);
      l2 += (f32x2){p0, p1};
    }

    __builtin_amdgcn_s_setprio(1);
#pragma unroll
    for (int ktl = 0; ktl < 2; ++ktl) {
      u32x4 pw;
#pragma unroll
      for (int i = 0; i < 4; ++i) pw[i] = W1[ktl * 4 + i];
      bf16x8 pfrag = __builtin_bit_cast(bf16x8, pw);
      bf16x8 vf0 = *reinterpret_cast<const bf16x8*>(Vb + voff[2 + ktl]);
      ot0 = __builtin_amdgcn_mfma_f32_32x32x16_bf16(vf0, pfrag, ot0, 0, 0, 0);
      bf16x8 vf1 = *reinterpret_cast<const bf16x8*>(Vb + voff[2 + ktl] + 4096);
      ot1 = __builtin_amdgcn_mfma_f32_32x32x16_bf16(vf1, pfrag, ot1, 0, 0, 0);
    }
    __builtin_amdgcn_s_setprio(0);

    if (more) {
      write_lds(buf ^ 1);
      __syncthreads();
      buf ^= 1;
    }
  }

  unsigned short* ob = Opb + ((size_t)half * N_TOK + q0 + q) * CDIM + h * HD;
#pragma unroll
  for (int g = 0; g < 4; ++g) {
    uint2 w;
    w.x = cvt_pk_bf16(ot0[4 * g + 0], ot0[4 * g + 1]);
    w.y = cvt_pk_bf16(ot0[4 * g + 2], ot0[4 * g + 3]);
    *reinterpret_cast<uint2*>(ob + g * 8 + hi * 4) = w;
    w.x = cvt_pk_bf16(ot1[4 * g + 0], ot1[4 * g + 1]);
    w.y = cvt_pk_bf16(ot1[4 * g + 2], ot1[4 * g + 3]);
    *reinterpret_cast<uint2*>(ob + 32 + g * 8 + hi * 4) = w;
  }
  float l = l2[0] + l2[1];
  l += __shfl_xor(l, 32);
  if (hi == 0)
    Lp[((size_t)half * NH + h) * N_TOK + q0 + q] = l;
}

// ---------------------------------------------------------------- combine halves (bf16 partials) -> bf16 Hb
__global__ __launch_bounds__(256) void combine_kernel(
    const unsigned short* __restrict__ Opb, const float* __restrict__ Lp,
    unsigned short* __restrict__ Hb) {
  int i = blockIdx.x * 256 + threadIdx.x;          // ushort8 index, N*C/8 total
  int n = i >> 7;
  int c = (i & 127) * 8;
  int h = c >> 6;
  float rl = 1.0f / (Lp[(size_t)h * N_TOK + n] +
                     Lp[((size_t)NH + h) * N_TOK + n]);
  uint4 a = reinterpret_cast<const uint4*>(Opb)[i];
  uint4 b = reinterpret_cast<const uint4*>(Opb + (size_t)N_TOK * CDIM)[i];
  auto comb = [&](unsigned int ua, unsigned int ub) -> unsigned int {
    float al = __builtin_bit_cast(float, ua << 16);
    float ah = __builtin_bit_cast(float, ua & 0xFFFF0000u);
    float bl = __builtin_bit_cast(float, ub << 16);
    float bh = __builtin_bit_cast(float, ub & 0xFFFF0000u);
    return cvt_pk_bf16((al + bl) * rl, (ah + bh) * rl);
  };
  uint4 o;
  o.x = comb(a.x, b.x);
  o.y = comb(a.y, b.y);
  o.z = comb(a.z, b.z);
  o.w = comb(a.w, b.w);
  reinterpret_cast<uint4*>(Hb)[i] = o;
}

// ---------------------------------------------------------------- launch
extern "C" void kernel_launch(void* const* d_in, const int* in_sizes, int n_in,
                              void* d_out, int out_size, void* d_ws, size_t ws_size,
                              hipStream_t stream) {
  const float* x    = (const float*)d_in[0];
  const float* Wqkv = (const float*)d_in[1];
  const float* bqkv = (const float*)d_in[2];
  const float* qg   = (const float*)d_in[3];
  const float* kg   = (const float*)d_in[4];
  const float* Wout = (const float*)d_in[5];
  const float* bout = (const float*)d_in[6];
  float* out = (float*)d_out;

  char* ws = (char*)d_ws;
  unsigned short* xb  = (unsigned short*)(ws);                       // 8MB
  unsigned short* w1b = (unsigned short*)(ws + ((size_t)8  << 20));  // 6MB
  unsigned short* w2b = (unsigned short*)(ws + ((size_t)14 << 20));  // 2MB
  unsigned short* Opb = (unsigned short*)(ws + ((size_t)16 << 20));  // 16MB bf16 partials
  float*          Lp  = (float*)         (ws + ((size_t)48 << 20));  // 0.5MB
  unsigned short* Qn  = (unsigned short*)(ws + ((size_t)64 << 20));
  unsigned short* Kn  = (unsigned short*)(ws + ((size_t)72 << 20));
  unsigned short* Vt  = (unsigned short*)(ws + ((size_t)80 << 20));
  unsigned short* Hb  = (unsigned short*)(ws + ((size_t)88 << 20));

  pack_bf16_kernel<<<8192, 256, 0, stream>>>(x, Wqkv, Wout, xb, w1b, w2b);
  gemm_qkv_kernel<<<dim3(32, 24), 256, 0, stream>>>(xb, w1b, bqkv, qg, kg,
                                                    Qn, Kn, Vt);
  flash_kernel<<<1024, 256, 0, stream>>>(Qn, Kn, Vt, Opb, Lp);
  combine_kernel<<<2048, 256, 0, stream>>>(Opb, Lp, Hb);
  gemm_bt_kernel<<<dim3(32, 8), 256, 0, stream>>>(Hb, w2b, bout, out,
                                                  N_TOK, CDIM, CDIM);
}